// Round 3
// baseline (1929.296 us; speedup 1.0000x reference)
//
#include <hip/hip_runtime.h>
#include <cmath>

typedef unsigned short ushort_t;
typedef unsigned char uchar_t;
typedef short short8 __attribute__((ext_vector_type(8)));
typedef float floatx4 __attribute__((ext_vector_type(4)));

#define B_GRAPH 512
#define ROWS 131072
#define IN_D 576                   // 512 LN'd feats + 64 ctx
#define FEAT_HID 1024
#define ATTN_HID 256
#define FEAT_OUT 256
#define NCHUNK 16
#define CH (ROWS / NCHUNK)         // 8192 rows per chunk
#define LDA 40                     // padded LDS row stride

// ---------- bf16 helpers (bit-level) ----------
__device__ __forceinline__ float bf2f(ushort_t h) {
    return __uint_as_float(((unsigned int)h) << 16);
}
__device__ __forceinline__ ushort_t f2bf(float f) {
    unsigned int u = __float_as_uint(f);
    u += 0x7fffu + ((u >> 16) & 1u);   // RNE
    return (ushort_t)(u >> 16);
}
__device__ __forceinline__ void load4bf(const ushort_t* p, float f[4]) {
    uint2 u = *(const uint2*)p;
    f[0] = __uint_as_float(u.x << 16);
    f[1] = __uint_as_float(u.x & 0xffff0000u);
    f[2] = __uint_as_float(u.y << 16);
    f[3] = __uint_as_float(u.y & 0xffff0000u);
}

// ---------- runtime dtype detection ----------
// flags[0]: 1 if float inputs are fp32, 0 if bf16
// flags[1]: 1 if mask is packed bytes, 0 if int32
__global__ void detect_kernel(const void* nodes, const void* maskp, int* flags) {
    const int t = threadIdx.x;
    const ushort_t* nb = (const ushort_t*)nodes;
    int cnt = 0;
    for (int i = t; i < 4096; i += 256) {
        unsigned e = ((unsigned)nb[i] >> 7) & 0xffu;   // bf16 exponent field
        if (e >= 147u) cnt++;                          // |x| >= 2^20: impossible for N(0,1) bf16
    }
    const unsigned* mw = (const unsigned*)maskp;
    int mcnt = 0;
    for (int i = t; i < 16384; i += 256) {             // 64 KiB: within either encoding
        if (mw[i] > 1u) mcnt++;
    }
    __shared__ int r1[256], r2[256];
    r1[t] = cnt; r2[t] = mcnt; __syncthreads();
    for (int off = 128; off > 0; off >>= 1) {
        if (t < off) { r1[t] += r1[t + off]; r2[t] += r2[t + off]; }
        __syncthreads();
    }
    if (t == 0) { flags[0] = (r1[0] > 64) ? 1 : 0; flags[1] = (r2[0] > 16) ? 1 : 0; }
}

__device__ __forceinline__ float loadany(const void* p, size_t i, int flag) {
    return flag ? ((const float*)p)[i] : bf2f(((const ushort_t*)p)[i]);
}
__device__ __forceinline__ bool maskany(const void* p, size_t i, int flagM) {
    return flagM ? (((const uchar_t*)p)[i] != 0) : (((const int*)p)[i] != 0);
}

// ---------- dtype-agnostic elementwise convert -> canonical bf16 ----------
__global__ void convert_kernel(const void* src, ushort_t* dst, int n, const int* flags) {
    const int flag = flags[0];
    int i = blockIdx.x * 256 + threadIdx.x;
    if (i >= n) return;
    dst[i] = f2bf(loadany(src, i, flag));
}

// ---------- weight transpose [R,C] -> canonical bf16 [C,R] ----------
__global__ void transpose_kernel(const void* src, ushort_t* dst, int R, int C,
                                 const int* flags) {
    const int flag = flags[0];
    int i = blockIdx.x * 256 + threadIdx.x;
    if (i >= R * C) return;
    int r = i / C, c = i - r * C;
    dst[(size_t)c * R + r] = f2bf(loadany(src, i, flag));
}

// ---------- LN over 512 + concat canonical ctx -> inp[CH][576] bf16 ----------
__global__ __launch_bounds__(256)
void ln_concat_kernel(const void* __restrict__ nodes, const void* __restrict__ pe,
                      const ushort_t* __restrict__ gcan,   // canonical globs [512*64]
                      const ushort_t* __restrict__ lg, const ushort_t* __restrict__ lb,
                      ushort_t* __restrict__ inp, int row0, const int* __restrict__ flags) {
    const int flag = flags[0];
    const int row  = blockIdx.x * 4 + (threadIdx.x >> 6);   // chunk-local
    const int lane = threadIdx.x & 63;
    const size_t grow = (size_t)row0 + row;
    float xa[4], xb[4];
    if (flag) {
        float4 a = *(const float4*)((const float*)nodes + grow * 256 + lane * 4);
        float4 b = *(const float4*)((const float*)pe    + grow * 256 + lane * 4);
        xa[0]=a.x; xa[1]=a.y; xa[2]=a.z; xa[3]=a.w;
        xb[0]=b.x; xb[1]=b.y; xb[2]=b.z; xb[3]=b.w;
    } else {
        load4bf((const ushort_t*)nodes + grow * 256 + lane * 4, xa);
        load4bf((const ushort_t*)pe    + grow * 256 + lane * 4, xb);
    }
    float s = 0.f, q = 0.f;
#pragma unroll
    for (int j = 0; j < 4; j++) { s += xa[j] + xb[j]; q += xa[j]*xa[j] + xb[j]*xb[j]; }
#pragma unroll
    for (int m = 1; m < 64; m <<= 1) { s += __shfl_xor(s, m, 64); q += __shfl_xor(q, m, 64); }
    const float mu   = s * (1.0f / 512.0f);
    const float var  = q * (1.0f / 512.0f) - mu * mu;
    const float rstd = rsqrtf(fmaxf(var, 0.f) + 1e-5f);
    float ga[4], gb[4], ba[4], bb[4];
    load4bf(lg + lane * 4, ga);  load4bf(lg + 256 + lane * 4, gb);
    load4bf(lb + lane * 4, ba);  load4bf(lb + 256 + lane * 4, bb);
    ushort_t r0[4], r1[4];
#pragma unroll
    for (int j = 0; j < 4; j++) {
        r0[j] = f2bf((xa[j] - mu) * rstd * ga[j] + ba[j]);
        r1[j] = f2bf((xb[j] - mu) * rstd * gb[j] + bb[j]);
    }
    ushort_t* op = inp + (size_t)row * IN_D;
    uint2 p0, p1;
    p0.x = (unsigned)r0[0] | ((unsigned)r0[1] << 16);
    p0.y = (unsigned)r0[2] | ((unsigned)r0[3] << 16);
    p1.x = (unsigned)r1[0] | ((unsigned)r1[1] << 16);
    p1.y = (unsigned)r1[2] | ((unsigned)r1[3] << 16);
    *(uint2*)(op + lane * 4)       = p0;
    *(uint2*)(op + 256 + lane * 4) = p1;
    op[512 + lane] = gcan[(grow >> 8) * 64 + lane];
}

// ---------- canonical-bf16 MFMA GEMM core (shared by both GEMM kernels) -----
// A[M,K] rm, Bt[N,K] rm. 128x128 tile, 4 waves 2x2, wave 64x64 = 4x4 MFMA
// 16x16x32 bf16. BK=32, padded LDS.
struct GemmCore {
    floatx4 acc[4][4];
    int wm, wn, r16, quad;
};
__device__ __forceinline__ void gemm_core(GemmCore& g,
        const ushort_t* __restrict__ A, const ushort_t* __restrict__ Bt,
        int m0, int n0, int K, ushort_t* As, ushort_t* Bs) {
    const int tid = threadIdx.x;
    const int wave = tid >> 6, lane = tid & 63;
    g.wm = (wave >> 1) * 64; g.wn = (wave & 1) * 64;
    g.r16 = lane & 15; g.quad = lane >> 4;
#pragma unroll
    for (int i = 0; i < 4; i++)
#pragma unroll
        for (int j = 0; j < 4; j++) g.acc[i][j] = (floatx4){0.f, 0.f, 0.f, 0.f};

    const int srow  = tid >> 1;
    const int skoff = (tid & 1) * 16;
    const ushort_t* Ag = A  + (size_t)(m0 + srow) * K + skoff;
    const ushort_t* Bg = Bt + (size_t)(n0 + srow) * K + skoff;
    ushort_t* Asd = As + srow * LDA + skoff;
    ushort_t* Bsd = Bs + srow * LDA + skoff;

    for (int k0 = 0; k0 < K; k0 += 32) {
        uint4 a0 = *(const uint4*)(Ag + k0);
        uint4 a1 = *(const uint4*)(Ag + k0 + 8);
        uint4 b0 = *(const uint4*)(Bg + k0);
        uint4 b1 = *(const uint4*)(Bg + k0 + 8);
        __syncthreads();
        *(uint4*)Asd       = a0;
        *(uint4*)(Asd + 8) = a1;
        *(uint4*)Bsd       = b0;
        *(uint4*)(Bsd + 8) = b1;
        __syncthreads();
        short8 af[4], bg[4];
#pragma unroll
        for (int i = 0; i < 4; i++)
            af[i] = *(const short8*)&As[(g.wm + i * 16 + g.r16) * LDA + g.quad * 8];
#pragma unroll
        for (int i = 0; i < 4; i++)
            bg[i] = *(const short8*)&Bs[(g.wn + i * 16 + g.r16) * LDA + g.quad * 8];
#pragma unroll
        for (int mi = 0; mi < 4; mi++)
#pragma unroll
            for (int ni = 0; ni < 4; ni++)
                g.acc[mi][ni] = __builtin_amdgcn_mfma_f32_16x16x32_bf16(
                    af[mi], bg[ni], g.acc[mi][ni], 0, 0, 0);
    }
}

// out = silu(acc + bias), canonical bf16 out [M,N] (chunk-local)
__global__ __launch_bounds__(256)
void gemm_silu(const ushort_t* __restrict__ A, const ushort_t* __restrict__ Bt,
               const ushort_t* __restrict__ bias, ushort_t* __restrict__ out,
               int N, int K) {
    __shared__ ushort_t As[128 * LDA];
    __shared__ ushort_t Bs[128 * LDA];
    const int m0 = blockIdx.x * 128, n0 = blockIdx.y * 128;
    GemmCore g;
    gemm_core(g, A, Bt, m0, n0, K, As, Bs);
#pragma unroll
    for (int mi = 0; mi < 4; mi++) {
        const int rbase = m0 + g.wm + mi * 16 + g.quad * 4;
#pragma unroll
        for (int ni = 0; ni < 4; ni++) {
            const int col = n0 + g.wn + ni * 16 + g.r16;
            const float bv = bf2f(bias[col]);
#pragma unroll
            for (int r = 0; r < 4; r++) {
                float v = g.acc[mi][ni][r] + bv;
                v = v / (1.0f + expf(-v));
                out[(size_t)(rbase + r) * N + col] = f2bf(v);
            }
        }
    }
}

// out = mask ? acc+bias+resid : resid  (writes d_out in detected dtype)
__global__ __launch_bounds__(256)
void gemm_out(const ushort_t* __restrict__ A, const ushort_t* __restrict__ Bt,
              const ushort_t* __restrict__ bias, void* __restrict__ out,
              const void* __restrict__ mask, const void* __restrict__ resid,
              int row0, int K, const int* __restrict__ flags) {
    __shared__ ushort_t As[128 * LDA];
    __shared__ ushort_t Bs[128 * LDA];
    const int flag = flags[0], flagM = flags[1];
    const int m0 = blockIdx.x * 128, n0 = blockIdx.y * 128;
    GemmCore g;
    gemm_core(g, A, Bt, m0, n0, K, As, Bs);
#pragma unroll
    for (int mi = 0; mi < 4; mi++) {
        const int rbase = m0 + g.wm + mi * 16 + g.quad * 4;
#pragma unroll
        for (int ni = 0; ni < 4; ni++) {
            const int col = n0 + g.wn + ni * 16 + g.r16;
            const float bv = bf2f(bias[col]);
#pragma unroll
            for (int r = 0; r < 4; r++) {
                const size_t grow = (size_t)row0 + rbase + r;
                const float nd = loadany(resid, grow * FEAT_OUT + col, flag);
                const bool mk = maskany(mask, grow, flagM);
                float v = mk ? (g.acc[mi][ni][r] + bv + nd) : nd;
                if (flag) ((float*)out)[grow * FEAT_OUT + col] = v;
                else      ((ushort_t*)out)[grow * FEAT_OUT + col] = f2bf(v);
            }
        }
    }
}

// ---------- scores = ha[.,256] @ aw2t[4,256]^T + ab2 ----------
__global__ __launch_bounds__(256)
void scores_kernel(const ushort_t* __restrict__ ha,   // chunk-local [CH,256]
                   const ushort_t* __restrict__ aw2t,
                   const ushort_t* __restrict__ ab2c,
                   float* __restrict__ scores, int row0) {
    const int row  = blockIdx.x * 4 + (threadIdx.x >> 6);
    const int lane = threadIdx.x & 63;
    float x[4];
    load4bf(ha + (size_t)row * 256 + lane * 4, x);
    float acc[4];
#pragma unroll
    for (int h = 0; h < 4; h++) {
        float wv[4];
        load4bf(aw2t + h * 256 + lane * 4, wv);
        acc[h] = x[0]*wv[0] + x[1]*wv[1] + x[2]*wv[2] + x[3]*wv[3];
    }
#pragma unroll
    for (int m = 1; m < 64; m <<= 1)
#pragma unroll
        for (int h = 0; h < 4; h++) acc[h] += __shfl_xor(acc[h], m, 64);
    if (lane == 0) {
#pragma unroll
        for (int h = 0; h < 4; h++)
            scores[((size_t)row0 + row) * 4 + h] = acc[h] + bf2f(ab2c[h]);
    }
}

// ---------- masked softmax over the 256 nodes of each graph ----------
__global__ __launch_bounds__(256)
void softmax_kernel(const float* __restrict__ scores, const void* __restrict__ mask,
                    float* __restrict__ w, const int* __restrict__ flags) {
    const int flagM = flags[1];
    const int b = blockIdx.x, n = threadIdx.x;
    const int idx = b * 256 + n;
    float4 s = *(const float4*)(scores + (size_t)idx * 4);
    s.x *= 0.0625f; s.y *= 0.0625f; s.z *= 0.0625f; s.w *= 0.0625f;  // /sqrt(256)
    const bool mk = maskany(mask, idx, flagM);
    __shared__ float4 red[256];
    float4 v;
    v.x = mk ? s.x : -3.0e38f; v.y = mk ? s.y : -3.0e38f;
    v.z = mk ? s.z : -3.0e38f; v.w = mk ? s.w : -3.0e38f;
    red[n] = v; __syncthreads();
    for (int off = 128; off > 0; off >>= 1) {
        if (n < off) {
            float4 o = red[n + off], c = red[n];
            c.x = fmaxf(c.x, o.x); c.y = fmaxf(c.y, o.y);
            c.z = fmaxf(c.z, o.z); c.w = fmaxf(c.w, o.w);
            red[n] = c;
        }
        __syncthreads();
    }
    float4 mx = red[0]; __syncthreads();
    float4 e;
    e.x = mk ? expf(s.x - mx.x) : 0.f; e.y = mk ? expf(s.y - mx.y) : 0.f;
    e.z = mk ? expf(s.z - mx.z) : 0.f; e.w = mk ? expf(s.w - mx.w) : 0.f;
    red[n] = e; __syncthreads();
    for (int off = 128; off > 0; off >>= 1) {
        if (n < off) {
            float4 o = red[n + off], c = red[n];
            c.x += o.x; c.y += o.y; c.z += o.z; c.w += o.w;
            red[n] = c;
        }
        __syncthreads();
    }
    float4 sm = red[0];
    const float ix = (sm.x > 0.f) ? 1.f / sm.x : 0.f;
    const float iy = (sm.y > 0.f) ? 1.f / sm.y : 0.f;
    const float iz = (sm.z > 0.f) ? 1.f / sm.z : 0.f;
    const float iw = (sm.w > 0.f) ? 1.f / sm.w : 0.f;
    float4 r; r.x = e.x * ix; r.y = e.y * iy; r.z = e.z * iz; r.w = e.w * iw;
    *(float4*)(w + (size_t)idx * 4) = r;
}

// ---------- pooled[b][d] = sum_n new_nodes[b,n,d] * w[b,n,d>>6] ----------
__global__ __launch_bounds__(256)
void pooled_kernel(const void* __restrict__ dout, const float* __restrict__ w,
                   const int* __restrict__ flags) {
    const int flag = flags[0];
    const int b = blockIdx.x, t = threadIdx.x;
    __shared__ float wsh[1024];
    const float* wb = w + (size_t)b * 1024;
    for (int i = t; i < 1024; i += 256) wsh[i] = wb[i];
    __syncthreads();
    const int h = t >> 6;
    float acc = 0.f;
    const size_t base = (size_t)b * 65536;
    if (flag) {
        const float* nn = (const float*)dout + base;
#pragma unroll 4
        for (int n = 0; n < 256; n++) acc += nn[(size_t)n * 256 + t] * wsh[n * 4 + h];
        ((float*)dout)[(size_t)ROWS * 256 + (size_t)b * 256 + t] = acc;
    } else {
        const ushort_t* nn = (const ushort_t*)dout + base;
#pragma unroll 4
        for (int n = 0; n < 256; n++) acc += bf2f(nn[(size_t)n * 256 + t]) * wsh[n * 4 + h];
        ((ushort_t*)dout)[(size_t)ROWS * 256 + (size_t)b * 256 + t] = f2bf(acc);
    }
}

extern "C" void kernel_launch(void* const* d_in, const int* in_sizes, int n_in,
                              void* d_out, int out_size, void* d_ws, size_t ws_size,
                              hipStream_t stream) {
    (void)in_sizes; (void)n_in; (void)out_size; (void)ws_size;
    const void* nodes = d_in[0];
    const void* pe    = d_in[1];
    const void* mask  = d_in[2];
    const void* globs = d_in[3];
    const void* ln_g  = d_in[4];
    const void* ln_b  = d_in[5];
    const void* fw1   = d_in[6];
    const void* fb1   = d_in[7];
    const void* fw2   = d_in[8];
    const void* fb2   = d_in[9];
    const void* aw1   = d_in[10];
    const void* ab1   = d_in[11];
    const void* aw2   = d_in[12];
    const void* ab2   = d_in[13];

    char* ws = (char*)d_ws;                              // total ~36.7 MB
    ushort_t* inp  = (ushort_t*)(ws);                    // CH*576*2  =  9,437,184
    ushort_t* h    = (ushort_t*)(ws + 9437184);          // CH*1024*2 = 16,777,216
    ushort_t* ha   = (ushort_t*)(ws + 26214400);         // CH*256*2  =  4,194,304
    float*    sc   = (float*)   (ws + 30408704);         // ROWS*4*4  =  2,097,152
    float*    wsm  = (float*)   (ws + 32505856);         // ROWS*4*4  =  2,097,152
    ushort_t* fw1t = (ushort_t*)(ws + 34603008);         // 1,179,648
    ushort_t* fw2t = (ushort_t*)(ws + 35782656);         //   524,288
    ushort_t* aw1t = (ushort_t*)(ws + 36306944);         //   294,912
    ushort_t* aw2t = (ushort_t*)(ws + 36601856);         //     2,048
    ushort_t* gcan = (ushort_t*)(ws + 36603904);         //    65,536
    ushort_t* lgc  = (ushort_t*)(ws + 36669440);         //     1,024
    ushort_t* lbc  = (ushort_t*)(ws + 36670464);         //     1,024
    ushort_t* fb1c = (ushort_t*)(ws + 36671488);         //     2,048
    ushort_t* fb2c = (ushort_t*)(ws + 36673536);         //       512
    ushort_t* ab1c = (ushort_t*)(ws + 36674048);         //       512
    ushort_t* ab2c = (ushort_t*)(ws + 36674560);         //        64
    int*      flags= (int*)     (ws + 36674624);         //         8

    detect_kernel<<<1, 256, 0, stream>>>(nodes, mask, flags);

    convert_kernel<<<128, 256, 0, stream>>>(globs, gcan, 32768, flags);
    convert_kernel<<<2, 256, 0, stream>>>(ln_g, lgc, 512, flags);
    convert_kernel<<<2, 256, 0, stream>>>(ln_b, lbc, 512, flags);
    convert_kernel<<<4, 256, 0, stream>>>(fb1, fb1c, 1024, flags);
    convert_kernel<<<1, 256, 0, stream>>>(fb2, fb2c, 256, flags);
    convert_kernel<<<1, 256, 0, stream>>>(ab1, ab1c, 256, flags);
    convert_kernel<<<1, 256, 0, stream>>>(ab2, ab2c, 4, flags);

    transpose_kernel<<<(576 * 1024 + 255) / 256, 256, 0, stream>>>(fw1, fw1t, 576, 1024, flags);
    transpose_kernel<<<(1024 * 256 + 255) / 256, 256, 0, stream>>>(fw2, fw2t, 1024, 256, flags);
    transpose_kernel<<<(576 * 256 + 255) / 256, 256, 0, stream>>>(aw1, aw1t, 576, 256, flags);
    transpose_kernel<<<(256 * 4 + 255) / 256, 256, 0, stream>>>(aw2, aw2t, 256, 4, flags);

    for (int c = 0; c < NCHUNK; c++) {
        const int row0 = c * CH;
        ln_concat_kernel<<<CH / 4, 256, 0, stream>>>(nodes, pe, gcan, lgc, lbc,
                                                     inp, row0, flags);
        gemm_silu<<<dim3(CH / 128, FEAT_HID / 128), 256, 0, stream>>>(
            inp, fw1t, fb1c, h, FEAT_HID, IN_D);
        gemm_silu<<<dim3(CH / 128, ATTN_HID / 128), 256, 0, stream>>>(
            inp, aw1t, ab1c, ha, ATTN_HID, IN_D);
        scores_kernel<<<CH / 4, 256, 0, stream>>>(ha, aw2t, ab2c, sc, row0);
        gemm_out<<<dim3(CH / 128, FEAT_OUT / 128), 256, 0, stream>>>(
            h, fw2t, fb2c, d_out, mask, nodes, row0, FEAT_HID, flags);
    }

    softmax_kernel<<<B_GRAPH, 256, 0, stream>>>(sc, mask, wsm, flags);
    pooled_kernel<<<B_GRAPH, 256, 0, stream>>>(d_out, wsm, flags);
}